// Round 10
// baseline (233.555 us; speedup 1.0000x reference)
//
#include <hip/hip_runtime.h>
#include <stdint.h>

// LinearAttention fused: qkv GEMM + dual softmax + linear attention + Wout GEMM + LayerNorm2d
// Shapes: b=32, c=128, n=64*64=4096, heads=4, dim_head=32.
// All GEMMs via v_mfma_f32_16x16x32_bf16 (fp32 accum).
//
// R6/R7: algebraic fold y = Wbig[b] @ qsm; frag-major Wbig; k3 LDS-staged. 159.9us.
// R8-R12: schedule variants neutral/regressed; k1 invariant ~43us, no pipe >45%.
// R13: v_cvt_pk_bf16_f32 FAILED correctness (not RNE-equivalent). Do not use.
// R14: k0 deleted (k1/k2 convert weights in-reg), k2a+k2b fused (ctxn in LDS).
//      157.5us; k1=41.2 dominant. LDS census: 192 redundant B-frag ds_read_b128
//      per subtile (every gemm wave re-reads the whole 64x128 x-tile) = largest
//      single pipe term (~19us LDS issue total).
// R15: gemm ownership re-tiled 32x64 -> 64x32: wave w = (row-group w>>1 of 64 rows,
//      col-group w&1 of 32 cols). wfa 16 short8 (64 VGPR, once per block); B-frags
//      16 -> 8 per wave per subtile (192 -> 96 total); 4 indep acc chains (ILP).
//      Epilogue re-indexed: rg 0-1 q (2 heads/wave), rg 2-3 k (+S reg accum, 2
//      partial writers per row -> S_part [b][16][128]), rg 4-5 v. ctx/staging/k3
//      unchanged; k2 S-loop 8->16.

constexpr int B_   = 32;
constexpr int C_   = 128;
constexpr int N_   = 4096;
constexpr int NSUB = 8;     // 64-wide n-subtiles per k1 block
constexpr int TPB_ = 8;     // k1 blocks per batch (4096 / 512)

using short8  = __attribute__((ext_vector_type(8))) short;
using short4v = __attribute__((ext_vector_type(4))) short;
using float4v = __attribute__((ext_vector_type(4))) float;

__device__ __forceinline__ unsigned short bf16_rne(float f) {
    union { float f; uint32_t u; } v; v.f = f;
    uint32_t u = v.u;
    u += 0x7FFFu + ((u >> 16) & 1u);   // round-to-nearest-even
    return (unsigned short)(u >> 16);
}

// workspace layout (bytes)
constexpr size_t OFF_SP   = 0;          // S partials [b][16][128] f32: 262144
constexpr size_t OFF_CTXP = 262144;     // ctx partials [b][8][4096] f32: 4194304 -> 4456448
constexpr size_t OFF_WBIG = 4456448;    // Wbig bf16 TILED: 1048576 -> 5505024
constexpr size_t OFF_QSM  = 5505024;    // q-softmax bf16 [b][n][h*32+d]: 33554432 -> 39059456
// total 39,059,456 bytes

// K1: per (b, 512-wide n-tile): 16 waves. Waves 0-11: gemm, wave w owns a 64-row x
// 32-col output slab (rg = w>>1, cg = w&1); wq frags (16 short8) converted from f32
// Wqkv once per block. Waves 12-15: stage x subtiles (T14 issue-early/write-late,
// double-buffered xs). S accumulated in k-wave registers.
__global__ __launch_bounds__(1024) void k1_qkv(const float* __restrict__ x,
                                               const float* __restrict__ Wqkv,
                                               unsigned short* __restrict__ qsm,
                                               float* __restrict__ ctx_part,
                                               float* __restrict__ S_part) {
    __shared__ __align__(16) unsigned short xs0[64 * 136];   // [n][c], stride 136 (dbuf A)
    __shared__ __align__(16) unsigned short xs1[64 * 136];   // dbuf B
    __shared__ __align__(16) unsigned short ek[128 * 72];    // [h*32+d][n], stride 72
    __shared__ __align__(16) unsigned short vsh[128 * 72];   // [h*32+e][n]

    const int b    = blockIdx.y;
    const int tblk = blockIdx.x;                 // 0..7
    const int tid  = threadIdx.x;

    const int lane = tid & 63;
    const int wv   = tid >> 6;                   // 0..15
    const int l15  = lane & 15;
    const int quad = lane >> 4;

    const float4v zero = {0.f, 0.f, 0.f, 0.f};

    const int rg = wv >> 1;                      // 0..5 (gemm waves): 64-row group
    const int cg = wv & 1;                       // col group (32 cols)

    // --- persistent wq fragments: f32 load + RNE convert, once per block ---
    short8 wfa[16];                              // [rt*4 + kk], rows rg*64 + rt*16 + l15
    if (wv < 12) {
        const float* wqp = Wqkv + ((size_t)(rg * 64 + l15)) * C_ + quad * 8;
        #pragma unroll
        for (int rt = 0; rt < 4; rt++) {
            #pragma unroll
            for (int kk = 0; kk < 4; kk++) {
                float4v f0 = *(const float4v*)(wqp + rt * 16 * C_ + kk * 32);
                float4v f1 = *(const float4v*)(wqp + rt * 16 * C_ + kk * 32 + 4);
                short8 w;
                #pragma unroll
                for (int j = 0; j < 4; j++) {
                    w[j]     = (short)bf16_rne(f0[j]);
                    w[4 + j] = (short)bf16_rne(f1[j]);
                }
                wfa[rt * 4 + kk] = w;
            }
        }
    }

    // --- staging lanes (waves 12-15): 256 threads, each 32 c-rows of one n ---
    const int sid = tid & 255;                   // for wv>=12: 0..255
    const int snl = sid & 63;                    // n within subtile
    const int scg = sid >> 6;                    // c group of 32
    const float* xbase = x + ((size_t)b * C_ + (size_t)scg * 32) * N_ + snl;
    float xv[32];                                // raw loads (issued one phase early)
    short8 c16[4];                               // converted subtile, write-late
    auto load_x = [&](int s) {
        const float* xp = xbase + (tblk * NSUB + s) * 64;
        #pragma unroll
        for (int i = 0; i < 32; i++) xv[i] = xp[(size_t)i * N_];
    };
    auto conv_x = [&]() {
        #pragma unroll
        for (int ii = 0; ii < 4; ii++) {
            short8 v8;
            #pragma unroll
            for (int j = 0; j < 8; j++) v8[j] = (short)bf16_rne(xv[ii * 8 + j]);
            c16[ii] = v8;
        }
    };
    auto store_c = [&](unsigned short* xs) {
        unsigned short* dst = &xs[snl * 136 + scg * 32];
        #pragma unroll
        for (int ii = 0; ii < 4; ii++) *(short8*)(dst + ii * 8) = c16[ii];
    };

    if (wv >= 12) {
        load_x(0); conv_x(); store_c(xs0);       // subtile 0 staged
        load_x(1);                               // subtile 1 loads in flight into phase 0
    }
    unsigned short* xs_cur = xs0;
    unsigned short* xs_nxt = xs1;

    float4v cacc = zero;                         // this wave's single ctx tile
    float sk[16] = {0.f};                        // S partial accum (k waves: rg 2-3)
    const int ch  = wv >> 2;                     // ctx tile coords (valid for all 16 wv)
    const int cdt = (wv >> 1) & 1;
    const int cet = wv & 1;

    for (int s = 0; s < NSUB; s++) {
        const int ns = (tblk * NSUB + s) * 64;
        __syncthreads();                         // A: xs_cur staged; ek/vsh free

        if (wv < 12) {
            #pragma unroll
            for (int c = 0; c < 2; c++) {
                const int ct = cg * 2 + c;
                short8 bfx[4];
                #pragma unroll
                for (int kk = 0; kk < 4; kk++)
                    bfx[kk] = *(const short8*)&xs_cur[(ct * 16 + l15) * 136 + kk * 32 + quad * 8];
                float4v acc[4] = {zero, zero, zero, zero};
                #pragma unroll
                for (int kk = 0; kk < 4; kk++) {
                    acc[0] = __builtin_amdgcn_mfma_f32_16x16x32_bf16(wfa[kk],      bfx[kk], acc[0], 0, 0, 0);
                    acc[1] = __builtin_amdgcn_mfma_f32_16x16x32_bf16(wfa[4 + kk],  bfx[kk], acc[1], 0, 0, 0);
                    acc[2] = __builtin_amdgcn_mfma_f32_16x16x32_bf16(wfa[8 + kk],  bfx[kk], acc[2], 0, 0, 0);
                    acc[3] = __builtin_amdgcn_mfma_f32_16x16x32_bf16(wfa[12 + kk], bfx[kk], acc[3], 0, 0, 0);
                }
                const int ncol = ct * 16 + l15;
                // C/D layout: col = l15, row = rt*16 + quad*4 + r (global row rg*64 + ...)
                if (rg < 2) {                    // q rows: 2 heads per wave
                    #pragma unroll
                    for (int hh = 0; hh < 2; hh++) {
                        float e[8], z = 0.f;
                        #pragma unroll
                        for (int t = 0; t < 2; t++)
                            #pragma unroll
                            for (int r = 0; r < 4; r++) {
                                e[t * 4 + r] = __expf(acc[hh * 2 + t][r]);
                                z += e[t * 4 + r];
                            }
                        z += __shfl_xor(z, 16, 64);
                        z += __shfl_xor(z, 32, 64);
                        const float iz = 1.0f / z;
                        unsigned short* qp = qsm + ((size_t)b * N_ + ns + ncol) * C_
                                           + (rg * 2 + hh) * 32 + quad * 4;
                        short4v s0, s1;
                        #pragma unroll
                        for (int r = 0; r < 4; r++) {
                            s0[r] = (short)bf16_rne(e[r] * iz);
                            s1[r] = (short)bf16_rne(e[4 + r] * iz);
                        }
                        *(short4v*)qp = s0;      // d = quad*4..+3
                        *(short4v*)(qp + 16) = s1;   // d = 16+quad*4..+3
                    }
                } else if (rg < 4) {             // k rows (rg-2)*64 .. +63: exp -> LDS + S
                    const int row0 = (rg - 2) * 64 + quad * 4;
                    #pragma unroll
                    for (int rt = 0; rt < 4; rt++)
                        #pragma unroll
                        for (int r = 0; r < 4; r++) {
                            const float ev = __expf(acc[rt][r]);
                            sk[rt * 4 + r] += ev;
                            ek[(row0 + rt * 16 + r) * 72 + ncol] = bf16_rne(ev);
                        }
                } else {                         // v rows (rg-4)*64 .. +63 -> LDS
                    const int row0 = (rg - 4) * 64 + quad * 4;
                    #pragma unroll
                    for (int rt = 0; rt < 4; rt++)
                        #pragma unroll
                        for (int r = 0; r < 4; r++)
                            vsh[(row0 + rt * 16 + r) * 72 + ncol] = bf16_rne(acc[rt][r]);
                }
            }
        } else {
            if (s + 1 < NSUB) { conv_x(); store_c(xs_nxt); }  // loads from phase s-1
            if (s + 2 < NSUB) load_x(s + 2);                  // issue only; consumed next phase
        }
        __syncthreads();                         // B: ek/vsh ready; xs_nxt staged

        // context: cacc[d][e] += sum_n expk[d][n] * v[e][n]  (one 16x16 tile per wave)
        {
            const unsigned short* ap = &ek[(ch * 32 + cdt * 16 + l15) * 72 + quad * 8];
            const unsigned short* bp = &vsh[(ch * 32 + cet * 16 + l15) * 72 + quad * 8];
            #pragma unroll
            for (int kk = 0; kk < 2; kk++) {
                short8 a  = *(const short8*)(ap + kk * 32);
                short8 bb = *(const short8*)(bp + kk * 32);
                cacc = __builtin_amdgcn_mfma_f32_16x16x32_bf16(a, bb, cacc, 0, 0, 0);
            }
        }
        { unsigned short* t = xs_cur; xs_cur = xs_nxt; xs_nxt = t; }
    }

    // write-out: plain stores, no atomics
    {
        float* cp = ctx_part + ((size_t)(b * TPB_ + tblk) << 12)
                  + ((ch * 32 + cdt * 16 + quad * 4) * 32 + cet * 16 + l15);
        #pragma unroll
        for (int r = 0; r < 4; r++) cp[r * 32] = cacc[r];
    }
    // S: k-waves (rg 2-3) reduce their register partials over the 16-lane col group.
    // Two partial writers per row (cg 0/1) -> S_part [b][tblk][2][128].
    if (rg == 2 || rg == 3) {
        float* sp = S_part + (((size_t)(b * TPB_ + tblk) * 2 + cg)) * 128 + (rg - 2) * 64;
        #pragma unroll
        for (int rt = 0; rt < 4; rt++)
            #pragma unroll
            for (int r = 0; r < 4; r++) {
                float a = sk[rt * 4 + r];
                a += __shfl_xor(a, 1, 64); a += __shfl_xor(a, 2, 64);
                a += __shfl_xor(a, 4, 64); a += __shfl_xor(a, 8, 64);
                if (l15 == 0) sp[rt * 16 + quad * 4 + r] = a;
            }
    }
}

// K2 (fused): one block per batch, 512 thr.
// Phase 1: Sinv[128] (16 partials). Phase 2: reduce 8 ctx partials, *Sinv, bf16 ->
// LDS ctxb [128][40]. Phase 3: Wbig = Wout @ blockdiag(ctxN) via 8 MFMAs/wave,
// Wout frags converted f32->bf16 in registers; written FRAG-MAJOR for k3.
__global__ __launch_bounds__(512) void k2_fused(const float* __restrict__ ctx_part,
                                                const float* __restrict__ S_part,
                                                const float* __restrict__ Wout,
                                                unsigned short* __restrict__ wbig) {
    __shared__ float Sinv[128];
    __shared__ __align__(16) unsigned short ctxb[128 * 40];  // [h*32+d][e]
    const int b   = blockIdx.x;
    const int tid = threadIdx.x;

    if (tid < 128) {
        float s = 0.f;
        #pragma unroll
        for (int t = 0; t < 16; t++)
            s += S_part[((size_t)b * 16 + t) * 128 + tid];
        Sinv[tid] = 1.0f / s;
    }
    __syncthreads();

    #pragma unroll
    for (int i = 0; i < 8; i++) {
        const int ei = i * 512 + tid;            // flat [hd][e]
        float v = 0.f;
        #pragma unroll
        for (int t = 0; t < TPB_; t++)
            v += ctx_part[((size_t)(b * TPB_ + t) << 12) + ei];
        ctxb[(ei >> 5) * 40 + (ei & 31)] = bf16_rne(v * Sinv[ei >> 5]);
    }
    __syncthreads();

    const int lane = tid & 63, wv = tid >> 6, l15 = lane & 15, quad = lane >> 4;
    const float4v zero = {0.f, 0.f, 0.f, 0.f};

    short8 a4[4];                                // Wout frags, f32 load + RNE convert
    {
        const float* wop = Wout + (wv * 16 + l15) * C_ + quad * 8;
        #pragma unroll
        for (int h = 0; h < 4; h++) {
            float4v f0 = *(const float4v*)(wop + h * 32);
            float4v f1 = *(const float4v*)(wop + h * 32 + 4);
            short8 w;
            #pragma unroll
            for (int j = 0; j < 4; j++) {
                w[j]     = (short)bf16_rne(f0[j]);
                w[4 + j] = (short)bf16_rne(f1[j]);
            }
            a4[h] = w;
        }
    }

    unsigned short* wb = wbig + (size_t)b * (C_ * C_);
    #pragma unroll
    for (int ht = 0; ht < 8; ht++) {             // hd-tile: head ht>>1, d-half ht&1
        const int h_ = ht >> 1;
        short8 bb = *(const short8*)&ctxb[(h_ * 32 + (ht & 1) * 16 + l15) * 40 + quad * 8];
        float4v c4 = __builtin_amdgcn_mfma_f32_16x16x32_bf16(a4[h_], bb, zero, 0, 0, 0);
        // value (r): o = wv*16+quad*4+r, hd = ht*16+l15
        const int c     = wv * 4 + (ht >> 1);
        const int quadp = (ht & 1) * 2 + (l15 >> 3);
        #pragma unroll
        for (int r = 0; r < 4; r++)
            wb[((c * 64 + quadp * 16 + quad * 4 + r) << 3) + (l15 & 7)] = bf16_rne(c4[r]);
    }
}

// K3: grid-stride persistent y = Wbig[b] @ qsm + bout, LayerNorm over c.
// 512 blocks (2/CU) x 512 thr; each block owns 256 n-cols = 2 tiles of 128.
// wbig (32KB frag-major) + bout/lnw/lnb staged into LDS ONCE per block; per tile the
// next tile's qsm frags are prefetched before the MFMA+store phase. One barrier total.
__global__ __launch_bounds__(512) void k3_out(const unsigned short* __restrict__ qsm,
                                              const unsigned short* __restrict__ wbig,
                                              const float* __restrict__ bout,
                                              const float* __restrict__ lnw,
                                              const float* __restrict__ lnb,
                                              float* __restrict__ out) {
    __shared__ __align__(16) unsigned short wls[16384];      // 32KB
    __shared__ float lnp[384];                               // bout | lnw | lnb

    const int b    = blockIdx.y;
    const int tseg = blockIdx.x;                 // 0..15: n-cols tseg*256 .. +255
    const int tid  = threadIdx.x;

    const int lane = tid & 63, wv = tid >> 6, l15 = lane & 15, quad = lane >> 4;
    const int nl = wv * 16 + l15;                // 0..127 within tile

    const float4v zero = {0.f, 0.f, 0.f, 0.f};
    const size_t n0base = (size_t)tseg * 256;

    // stage Wbig[b] 32KB -> LDS (linear: thread t copies 16B chunks t, t+512, ...)
    short8 st[4];
    {
        const short8* src = (const short8*)(wbig + (size_t)b * (C_ * C_));
        #pragma unroll
        for (int i = 0; i < 4; i++) st[i] = src[i * 512 + tid];
    }
    if (tid < 128) {
        lnp[tid]       = bout[tid];
        lnp[128 + tid] = lnw[tid];
        lnp[256 + tid] = lnb[tid];
    }
    // first tile's qsm B-frags (independent; overlap the stage)
    short8 bq[4], bqn[4];
    {
        const unsigned short* qp = qsm + ((size_t)b * N_ + n0base + nl) * C_ + quad * 8;
        #pragma unroll
        for (int kk = 0; kk < 4; kk++) bq[kk] = *(const short8*)(qp + kk * 32);
    }
    #pragma unroll
    for (int i = 0; i < 4; i++)
        *(short8*)&wls[(i * 512 + tid) * 8] = st[i];
    __syncthreads();

    #pragma unroll
    for (int t = 0; t < 2; t++) {
        const size_t n = n0base + t * 128 + nl;
        if (t == 0) {                            // prefetch next tile's frags
            const unsigned short* qp = qsm + ((size_t)b * N_ + n0base + 128 + nl) * C_ + quad * 8;
            #pragma unroll
            for (int kk = 0; kk < 4; kk++) bqn[kk] = *(const short8*)(qp + kk * 32);
        }

        float4v acc[8];
        #pragma unroll
        for (int ot = 0; ot < 8; ot++) {
            float4v a = zero;
            #pragma unroll
            for (int kk = 0; kk < 4; kk++) {
                short8 w = *(const short8*)&wls[((ot * 4 + kk) * 64 + lane) * 8];
                a = __builtin_amdgcn_mfma_f32_16x16x32_bf16(w, bq[kk], a, 0, 0, 0);
            }
            acc[ot] = a;
        }

        // bias + LayerNorm over the 128 channels of this column
        float sum = 0.f, sq = 0.f;
        #pragma unroll
        for (int ot = 0; ot < 8; ot++) {
            #pragma unroll
            for (int r = 0; r < 4; r++) {
                const int o = ot * 16 + quad * 4 + r;
                const float y = acc[ot][r] + lnp[o];
                acc[ot][r] = y;
                sum += y; sq += y * y;
            }
        }
        sum += __shfl_xor(sum, 16, 64);
        sum += __shfl_xor(sum, 32, 64);
        sq  += __shfl_xor(sq, 16, 64);
        sq  += __shfl_xor(sq, 32, 64);
        const float mean = sum * (1.0f / 128.0f);
        const float var  = sq * (1.0f / 128.0f) - mean * mean;   // biased, matches jnp.var
        const float rstd = rsqrtf(var + 1e-5f);

        #pragma unroll
        for (int ot = 0; ot < 8; ot++) {
            #pragma unroll
            for (int r = 0; r < 4; r++) {
                const int o = ot * 16 + quad * 4 + r;
                out[((size_t)b * C_ + o) * N_ + n] = (acc[ot][r] - mean) * rstd * lnp[128 + o] + lnp[256 + o];
            }
        }

        #pragma unroll
        for (int kk = 0; kk < 4; kk++) bq[kk] = bqn[kk];
    }
}

extern "C" void kernel_launch(void* const* d_in, const int* in_sizes, int n_in,
                              void* d_out, int out_size, void* d_ws, size_t ws_size,
                              hipStream_t stream) {
    const float* x    = (const float*)d_in[0];
    const float* Wqkv = (const float*)d_in[1];
    const float* Wout = (const float*)d_in[2];
    const float* bout = (const float*)d_in[3];
    const float* lnw  = (const float*)d_in[4];
    const float* lnb  = (const float*)d_in[5];
    float* out = (float*)d_out;

    char* ws = (char*)d_ws;
    float* S_part        = (float*)(ws + OFF_SP);
    float* ctx_part      = (float*)(ws + OFF_CTXP);
    unsigned short* wbig = (unsigned short*)(ws + OFF_WBIG);
    unsigned short* qsm  = (unsigned short*)(ws + OFF_QSM);

    k1_qkv<<<dim3(TPB_, B_), 1024, 0, stream>>>(x, Wqkv, qsm, ctx_part, S_part);
    k2_fused<<<B_, 512, 0, stream>>>(ctx_part, S_part, Wout, wbig);
    k3_out<<<dim3(16, B_), 512, 0, stream>>>(qsm, wbig, bout, lnw, lnb, out);
}

// Round 11
// 213.825 us; speedup vs baseline: 1.0923x; 1.0923x over previous
//
#include <hip/hip_runtime.h>
#include <stdint.h>

// LinearAttention fused: qkv GEMM + dual softmax + linear attention + Wout GEMM + LayerNorm2d
// Shapes: b=32, c=128, n=64*64=4096, heads=4, dim_head=32.
// All GEMMs via v_mfma_f32_16x16x32_bf16 (fp32 accum).
//
// R6/R7: algebraic fold y = Wbig[b] @ qsm; frag-major Wbig; k3 LDS-staged. 159.9us.
// R8-R12: schedule variants neutral/regressed; k1 invariant ~43us, no pipe >45%.
// R13: v_cvt_pk_bf16_f32 FAILED correctness (not RNE-equivalent). Do not use.
// R14: k0 deleted, k2a+k2b fused. 157.5us (best); k1=41.2 dominant; 192 redundant
//      B-frag ds_read_b128/subtile = largest pipe term.
// R15: 64x32 gemm re-tile REGRESSED (233us) -- NOT the tiling: compiler kept
//      VGPR=64 (default occupancy heuristic) vs ~120 live -> scratch spill storm
//      (WRITE 38->103MB, FETCH 34->53MB, occ 1.3%). Tiling untested, not refuted.
// R16: same 64x32 tiling + __launch_bounds__(1024, 4): 16 waves = 1 block/CU,
//      VGPR cap 512/4 = 128 (R10/R11: k1 occupancy-insensitive, 2nd block free).
//      sk[16] reg array dropped (-16 VGPR): S back to R9-style per-subtile LDS
//      pass (measured neutral R11->R12). Peak ~110 <= 128.

constexpr int B_   = 32;
constexpr int C_   = 128;
constexpr int N_   = 4096;
constexpr int NSUB = 8;     // 64-wide n-subtiles per k1 block
constexpr int TPB_ = 8;     // k1 blocks per batch (4096 / 512)

using short8  = __attribute__((ext_vector_type(8))) short;
using short4v = __attribute__((ext_vector_type(4))) short;
using float4v = __attribute__((ext_vector_type(4))) float;

__device__ __forceinline__ unsigned short bf16_rne(float f) {
    union { float f; uint32_t u; } v; v.f = f;
    uint32_t u = v.u;
    u += 0x7FFFu + ((u >> 16) & 1u);   // round-to-nearest-even
    return (unsigned short)(u >> 16);
}
__device__ __forceinline__ float bf2f(unsigned short h) {
    union { uint32_t u; float f; } v; v.u = ((uint32_t)h) << 16; return v.f;
}

// workspace layout (bytes)
constexpr size_t OFF_SP   = 0;          // S partials [b][8][128] f32: 131072
constexpr size_t OFF_CTXP = 131072;     // ctx partials [b][8][4096] f32: 4194304 -> 4325376
constexpr size_t OFF_WBIG = 4325376;    // Wbig bf16 TILED: 1048576 -> 5373952
constexpr size_t OFF_QSM  = 5373952;    // q-softmax bf16 [b][n][h*32+d]: 33554432 -> 38928384
// total 38,928,384 bytes

// K1: per (b, 512-wide n-tile): 16 waves, 1 block/CU (launch_bounds 1024,4 -> VGPR
// cap 128). Waves 0-11: gemm, wave w owns a 64-row x 32-col output slab (rg = w>>1,
// cg = w&1); wfa (16 short8 = 64 VGPR) converted from f32 Wqkv once per block.
// Waves 12-15: stage x subtiles (T14 issue-early/write-late, double-buffered xs).
// S via per-subtile LDS pass (all 16 waves, 1 reg) -- measured neutral in R11->R12.
__global__ __launch_bounds__(1024, 4) void k1_qkv(const float* __restrict__ x,
                                                  const float* __restrict__ Wqkv,
                                                  unsigned short* __restrict__ qsm,
                                                  float* __restrict__ ctx_part,
                                                  float* __restrict__ S_part) {
    __shared__ __align__(16) unsigned short xs0[64 * 136];   // [n][c], stride 136 (dbuf A)
    __shared__ __align__(16) unsigned short xs1[64 * 136];   // dbuf B
    __shared__ __align__(16) unsigned short ek[128 * 72];    // [h*32+d][n], stride 72
    __shared__ __align__(16) unsigned short vsh[128 * 72];   // [h*32+e][n]

    const int b    = blockIdx.y;
    const int tblk = blockIdx.x;                 // 0..7
    const int tid  = threadIdx.x;

    const int lane = tid & 63;
    const int wv   = tid >> 6;                   // 0..15
    const int l15  = lane & 15;
    const int quad = lane >> 4;

    const float4v zero = {0.f, 0.f, 0.f, 0.f};

    const int rg = wv >> 1;                      // 0..5 (gemm waves): 64-row group
    const int cg = wv & 1;                       // col group (32 cols)

    // --- persistent wq fragments: f32 load + RNE convert, once per block ---
    short8 wfa[16];                              // [rt*4 + kk], rows rg*64 + rt*16 + l15
    if (wv < 12) {
        const float* wqp = Wqkv + ((size_t)(rg * 64 + l15)) * C_ + quad * 8;
        #pragma unroll
        for (int rt = 0; rt < 4; rt++) {
            #pragma unroll
            for (int kk = 0; kk < 4; kk++) {
                float4v f0 = *(const float4v*)(wqp + rt * 16 * C_ + kk * 32);
                float4v f1 = *(const float4v*)(wqp + rt * 16 * C_ + kk * 32 + 4);
                short8 w;
                #pragma unroll
                for (int j = 0; j < 4; j++) {
                    w[j]     = (short)bf16_rne(f0[j]);
                    w[4 + j] = (short)bf16_rne(f1[j]);
                }
                wfa[rt * 4 + kk] = w;
            }
        }
    }

    // --- staging lanes (waves 12-15): 256 threads, each 32 c-rows of one n ---
    const int sid = tid & 255;                   // for wv>=12: 0..255
    const int snl = sid & 63;                    // n within subtile
    const int scg = sid >> 6;                    // c group of 32
    const float* xbase = x + ((size_t)b * C_ + (size_t)scg * 32) * N_ + snl;
    float xv[32];                                // raw loads (issued one phase early)
    short8 c16[4];                               // converted subtile, write-late
    auto load_x = [&](int s) {
        const float* xp = xbase + (tblk * NSUB + s) * 64;
        #pragma unroll
        for (int i = 0; i < 32; i++) xv[i] = xp[(size_t)i * N_];
    };
    auto conv_x = [&]() {
        #pragma unroll
        for (int ii = 0; ii < 4; ii++) {
            short8 v8;
            #pragma unroll
            for (int j = 0; j < 8; j++) v8[j] = (short)bf16_rne(xv[ii * 8 + j]);
            c16[ii] = v8;
        }
    };
    auto store_c = [&](unsigned short* xs) {
        unsigned short* dst = &xs[snl * 136 + scg * 32];
        #pragma unroll
        for (int ii = 0; ii < 4; ii++) *(short8*)(dst + ii * 8) = c16[ii];
    };

    if (wv >= 12) {
        load_x(0); conv_x(); store_c(xs0);       // subtile 0 staged
        load_x(1);                               // subtile 1 loads in flight into phase 0
    }
    unsigned short* xs_cur = xs0;
    unsigned short* xs_nxt = xs1;

    float4v cacc = zero;                         // this wave's single ctx tile
    float s_acc  = 0.f;                          // S partial accum (LDS pass)
    const int ch  = wv >> 2;                     // ctx tile coords (valid for all 16 wv)
    const int cdt = (wv >> 1) & 1;
    const int cet = wv & 1;

    for (int s = 0; s < NSUB; s++) {
        const int ns = (tblk * NSUB + s) * 64;
        __syncthreads();                         // A: xs_cur staged; ek/vsh free

        if (wv < 12) {
            #pragma unroll
            for (int c = 0; c < 2; c++) {
                const int ct = cg * 2 + c;
                short8 bfx[4];
                #pragma unroll
                for (int kk = 0; kk < 4; kk++)
                    bfx[kk] = *(const short8*)&xs_cur[(ct * 16 + l15) * 136 + kk * 32 + quad * 8];
                float4v acc[4] = {zero, zero, zero, zero};
                #pragma unroll
                for (int kk = 0; kk < 4; kk++) {
                    acc[0] = __builtin_amdgcn_mfma_f32_16x16x32_bf16(wfa[kk],      bfx[kk], acc[0], 0, 0, 0);
                    acc[1] = __builtin_amdgcn_mfma_f32_16x16x32_bf16(wfa[4 + kk],  bfx[kk], acc[1], 0, 0, 0);
                    acc[2] = __builtin_amdgcn_mfma_f32_16x16x32_bf16(wfa[8 + kk],  bfx[kk], acc[2], 0, 0, 0);
                    acc[3] = __builtin_amdgcn_mfma_f32_16x16x32_bf16(wfa[12 + kk], bfx[kk], acc[3], 0, 0, 0);
                }
                const int ncol = ct * 16 + l15;
                // C/D layout: col = l15, row = rt*16 + quad*4 + r (global row rg*64 + ...)
                if (rg < 2) {                    // q rows: 2 heads per wave
                    #pragma unroll
                    for (int hh = 0; hh < 2; hh++) {
                        float e[8], z = 0.f;
                        #pragma unroll
                        for (int t = 0; t < 2; t++)
                            #pragma unroll
                            for (int r = 0; r < 4; r++) {
                                e[t * 4 + r] = __expf(acc[hh * 2 + t][r]);
                                z += e[t * 4 + r];
                            }
                        z += __shfl_xor(z, 16, 64);
                        z += __shfl_xor(z, 32, 64);
                        const float iz = 1.0f / z;
                        unsigned short* qp = qsm + ((size_t)b * N_ + ns + ncol) * C_
                                           + (rg * 2 + hh) * 32 + quad * 4;
                        short4v s0, s1;
                        #pragma unroll
                        for (int r = 0; r < 4; r++) {
                            s0[r] = (short)bf16_rne(e[r] * iz);
                            s1[r] = (short)bf16_rne(e[4 + r] * iz);
                        }
                        *(short4v*)qp = s0;      // d = quad*4..+3
                        *(short4v*)(qp + 16) = s1;   // d = 16+quad*4..+3
                    }
                } else if (rg < 4) {             // k rows (rg-2)*64 .. +63: exp -> LDS
                    const int row0 = (rg - 2) * 64 + quad * 4;
                    #pragma unroll
                    for (int rt = 0; rt < 4; rt++)
                        #pragma unroll
                        for (int r = 0; r < 4; r++)
                            ek[(row0 + rt * 16 + r) * 72 + ncol] = bf16_rne(__expf(acc[rt][r]));
                } else {                         // v rows (rg-4)*64 .. +63 -> LDS
                    const int row0 = (rg - 4) * 64 + quad * 4;
                    #pragma unroll
                    for (int rt = 0; rt < 4; rt++)
                        #pragma unroll
                        for (int r = 0; r < 4; r++)
                            vsh[(row0 + rt * 16 + r) * 72 + ncol] = bf16_rne(acc[rt][r]);
                }
            }
        } else {
            if (s + 1 < NSUB) { conv_x(); store_c(xs_nxt); }  // loads from phase s-1
            if (s + 2 < NSUB) load_x(s + 2);                  // issue only; consumed next phase
        }
        __syncthreads();                         // B: ek/vsh ready; xs_nxt staged

        // context: cacc[d][e] += sum_n expk[d][n] * v[e][n]  (one 16x16 tile per wave)
        {
            const unsigned short* ap = &ek[(ch * 32 + cdt * 16 + l15) * 72 + quad * 8];
            const unsigned short* bp = &vsh[(ch * 32 + cet * 16 + l15) * 72 + quad * 8];
            #pragma unroll
            for (int kk = 0; kk < 2; kk++) {
                short8 a  = *(const short8*)(ap + kk * 32);
                short8 bb = *(const short8*)(bp + kk * 32);
                cacc = __builtin_amdgcn_mfma_f32_16x16x32_bf16(a, bb, cacc, 0, 0, 0);
            }
        }
        {   // S partial sums: 1024 threads = 128 rows x 8 threads x 8 elems
            const unsigned short* ep = &ek[(tid >> 3) * 72 + (tid & 7) * 8];
            short8 e0 = *(const short8*)ep;      // one ds_read_b128
            float ss = 0.f;
            #pragma unroll
            for (int j = 0; j < 8; j++) ss += bf2f((unsigned short)e0[j]);
            s_acc += ss;
        }
        { unsigned short* t = xs_cur; xs_cur = xs_nxt; xs_nxt = t; }
    }

    // write-out: plain stores, no atomics
    {
        float* cp = ctx_part + ((size_t)(b * TPB_ + tblk) << 12)
                  + ((ch * 32 + cdt * 16 + quad * 4) * 32 + cet * 16 + l15);
        #pragma unroll
        for (int r = 0; r < 4; r++) cp[r * 32] = cacc[r];
    }
    {
        float ss = s_acc;
        ss += __shfl_xor(ss, 1, 64);
        ss += __shfl_xor(ss, 2, 64);
        ss += __shfl_xor(ss, 4, 64);
        if ((tid & 7) == 0)
            S_part[(size_t)(b * TPB_ + tblk) * 128 + (tid >> 3)] = ss;
    }
}

// K2 (fused): one block per batch, 512 thr.
// Phase 1: Sinv[128] (8 partials). Phase 2: reduce 8 ctx partials, *Sinv, bf16 ->
// LDS ctxb [128][40]. Phase 3: Wbig = Wout @ blockdiag(ctxN) via 8 MFMAs/wave,
// Wout frags converted f32->bf16 in registers; written FRAG-MAJOR for k3.
__global__ __launch_bounds__(512) void k2_fused(const float* __restrict__ ctx_part,
                                                const float* __restrict__ S_part,
                                                const float* __restrict__ Wout,
                                                unsigned short* __restrict__ wbig) {
    __shared__ float Sinv[128];
    __shared__ __align__(16) unsigned short ctxb[128 * 40];  // [h*32+d][e]
    const int b   = blockIdx.x;
    const int tid = threadIdx.x;

    if (tid < 128) {
        float s = 0.f;
        #pragma unroll
        for (int t = 0; t < TPB_; t++)
            s += S_part[(size_t)(b * TPB_ + t) * 128 + tid];
        Sinv[tid] = 1.0f / s;
    }
    __syncthreads();

    #pragma unroll
    for (int i = 0; i < 8; i++) {
        const int ei = i * 512 + tid;            // flat [hd][e]
        float v = 0.f;
        #pragma unroll
        for (int t = 0; t < TPB_; t++)
            v += ctx_part[((size_t)(b * TPB_ + t) << 12) + ei];
        ctxb[(ei >> 5) * 40 + (ei & 31)] = bf16_rne(v * Sinv[ei >> 5]);
    }
    __syncthreads();

    const int lane = tid & 63, wv = tid >> 6, l15 = lane & 15, quad = lane >> 4;
    const float4v zero = {0.f, 0.f, 0.f, 0.f};

    short8 a4[4];                                // Wout frags, f32 load + RNE convert
    {
        const float* wop = Wout + (wv * 16 + l15) * C_ + quad * 8;
        #pragma unroll
        for (int h = 0; h < 4; h++) {
            float4v f0 = *(const float4v*)(wop + h * 32);
            float4v f1 = *(const float4v*)(wop + h * 32 + 4);
            short8 w;
            #pragma unroll
            for (int j = 0; j < 4; j++) {
                w[j]     = (short)bf16_rne(f0[j]);
                w[4 + j] = (short)bf16_rne(f1[j]);
            }
            a4[h] = w;
        }
    }

    unsigned short* wb = wbig + (size_t)b * (C_ * C_);
    #pragma unroll
    for (int ht = 0; ht < 8; ht++) {             // hd-tile: head ht>>1, d-half ht&1
        const int h_ = ht >> 1;
        short8 bb = *(const short8*)&ctxb[(h_ * 32 + (ht & 1) * 16 + l15) * 40 + quad * 8];
        float4v c4 = __builtin_amdgcn_mfma_f32_16x16x32_bf16(a4[h_], bb, zero, 0, 0, 0);
        // value (r): o = wv*16+quad*4+r, hd = ht*16+l15
        const int c     = wv * 4 + (ht >> 1);
        const int quadp = (ht & 1) * 2 + (l15 >> 3);
        #pragma unroll
        for (int r = 0; r < 4; r++)
            wb[((c * 64 + quadp * 16 + quad * 4 + r) << 3) + (l15 & 7)] = bf16_rne(c4[r]);
    }
}

// K3: grid-stride persistent y = Wbig[b] @ qsm + bout, LayerNorm over c.
// 512 blocks (2/CU) x 512 thr; each block owns 256 n-cols = 2 tiles of 128.
// wbig (32KB frag-major) + bout/lnw/lnb staged into LDS ONCE per block; per tile the
// next tile's qsm frags are prefetched before the MFMA+store phase. One barrier total.
__global__ __launch_bounds__(512) void k3_out(const unsigned short* __restrict__ qsm,
                                              const unsigned short* __restrict__ wbig,
                                              const float* __restrict__ bout,
                                              const float* __restrict__ lnw,
                                              const float* __restrict__ lnb,
                                              float* __restrict__ out) {
    __shared__ __align__(16) unsigned short wls[16384];      // 32KB
    __shared__ float lnp[384];                               // bout | lnw | lnb

    const int b    = blockIdx.y;
    const int tseg = blockIdx.x;                 // 0..15: n-cols tseg*256 .. +255
    const int tid  = threadIdx.x;

    const int lane = tid & 63, wv = tid >> 6, l15 = lane & 15, quad = lane >> 4;
    const int nl = wv * 16 + l15;                // 0..127 within tile

    const float4v zero = {0.f, 0.f, 0.f, 0.f};
    const size_t n0base = (size_t)tseg * 256;

    // stage Wbig[b] 32KB -> LDS (linear: thread t copies 16B chunks t, t+512, ...)
    short8 st[4];
    {
        const short8* src = (const short8*)(wbig + (size_t)b * (C_ * C_));
        #pragma unroll
        for (int i = 0; i < 4; i++) st[i] = src[i * 512 + tid];
    }
    if (tid < 128) {
        lnp[tid]       = bout[tid];
        lnp[128 + tid] = lnw[tid];
        lnp[256 + tid] = lnb[tid];
    }
    // first tile's qsm B-frags (independent; overlap the stage)
    short8 bq[4], bqn[4];
    {
        const unsigned short* qp = qsm + ((size_t)b * N_ + n0base + nl) * C_ + quad * 8;
        #pragma unroll
        for (int kk = 0; kk < 4; kk++) bq[kk] = *(const short8*)(qp + kk * 32);
    }
    #pragma unroll
    for (int i = 0; i < 4; i++)
        *(short8*)&wls[(i * 512 + tid) * 8] = st[i];
    __syncthreads();

    #pragma unroll
    for (int t = 0; t < 2; t++) {
        const size_t n = n0base + t * 128 + nl;
        if (t == 0) {                            // prefetch next tile's frags
            const unsigned short* qp = qsm + ((size_t)b * N_ + n0base + 128 + nl) * C_ + quad * 8;
            #pragma unroll
            for (int kk = 0; kk < 4; kk++) bqn[kk] = *(const short8*)(qp + kk * 32);
        }

        float4v acc[8];
        #pragma unroll
        for (int ot = 0; ot < 8; ot++) {
            float4v a = zero;
            #pragma unroll
            for (int kk = 0; kk < 4; kk++) {
                short8 w = *(const short8*)&wls[((ot * 4 + kk) * 64 + lane) * 8];
                a = __builtin_amdgcn_mfma_f32_16x16x32_bf16(w, bq[kk], a, 0, 0, 0);
            }
            acc[ot] = a;
        }

        // bias + LayerNorm over the 128 channels of this column
        float sum = 0.f, sq = 0.f;
        #pragma unroll
        for (int ot = 0; ot < 8; ot++) {
            #pragma unroll
            for (int r = 0; r < 4; r++) {
                const int o = ot * 16 + quad * 4 + r;
                const float y = acc[ot][r] + lnp[o];
                acc[ot][r] = y;
                sum += y; sq += y * y;
            }
        }
        sum += __shfl_xor(sum, 16, 64);
        sum += __shfl_xor(sum, 32, 64);
        sq  += __shfl_xor(sq, 16, 64);
        sq  += __shfl_xor(sq, 32, 64);
        const float mean = sum * (1.0f / 128.0f);
        const float var  = sq * (1.0f / 128.0f) - mean * mean;   // biased, matches jnp.var
        const float rstd = rsqrtf(var + 1e-5f);

        #pragma unroll
        for (int ot = 0; ot < 8; ot++) {
            #pragma unroll
            for (int r = 0; r < 4; r++) {
                const int o = ot * 16 + quad * 4 + r;
                out[((size_t)b * C_ + o) * N_ + n] = (acc[ot][r] - mean) * rstd * lnp[128 + o] + lnp[256 + o];
            }
        }

        #pragma unroll
        for (int kk = 0; kk < 4; kk++) bq[kk] = bqn[kk];
    }
}

extern "C" void kernel_launch(void* const* d_in, const int* in_sizes, int n_in,
                              void* d_out, int out_size, void* d_ws, size_t ws_size,
                              hipStream_t stream) {
    const float* x    = (const float*)d_in[0];
    const float* Wqkv = (const float*)d_in[1];
    const float* Wout = (const float*)d_in[2];
    const float* bout = (const float*)d_in[3];
    const float* lnw  = (const float*)d_in[4];
    const float* lnb  = (const float*)d_in[5];
    float* out = (float*)d_out;

    char* ws = (char*)d_ws;
    float* S_part        = (float*)(ws + OFF_SP);
    float* ctx_part      = (float*)(ws + OFF_CTXP);
    unsigned short* wbig = (unsigned short*)(ws + OFF_WBIG);
    unsigned short* qsm  = (unsigned short*)(ws + OFF_QSM);

    k1_qkv<<<dim3(TPB_, B_), 1024, 0, stream>>>(x, Wqkv, qsm, ctx_part, S_part);
    k2_fused<<<B_, 512, 0, stream>>>(ctx_part, S_part, Wout, wbig);
    k3_out<<<dim3(16, B_), 512, 0, stream>>>(qsm, wbig, bout, lnw, lnb, out);
}

// Round 12
// 157.984 us; speedup vs baseline: 1.4783x; 1.3535x over previous
//
#include <hip/hip_runtime.h>
#include <stdint.h>

// LinearAttention fused: qkv GEMM + dual softmax + linear attention + Wout GEMM + LayerNorm2d
// Shapes: b=32, c=128, n=64*64=4096, heads=4, dim_head=32.
// All GEMMs via v_mfma_f32_16x16x32_bf16 (fp32 accum).
//
// R5: k1 rebuilt: 1024-thr blocks, 16 waves, wq frags persistent in VGPRs. 181us.
// R6: algebraic fold y = (Wout @ blockdiag_h(ctxN)) @ qsm = Wbig[b] @ qsm.
// R7: Wbig frag-major + k3 LDS-staged inner loop; k2 split. 159.9us (-17.8).
// R8-R12: five k1/k3 schedule variants all neutral/regressed; k1 invariant ~43us
//      across 1 vs 2 blocks/CU, 9 vs 16 barriers; no pipe >45%.
// R13: v_cvt_pk_bf16_f32 FAILED correctness (not RNE-equivalent). Do not use.
// R14: k0 deleted (k1/k2 convert weights in-reg), k2a+k2b fused (ctxn in LDS).
//      157.5us (BEST); k1=41.2 dominant.
// R15: 64x32 gemm re-tile: VGPR pinned 64 -> spill storm, 233us. R16: retry with
//      __launch_bounds__(1024,4): compiler STILL caps at 64 VGPR, spills, 213us.
//      hipcc will not allocate >64 VGPR for this 1024-thr kernel shape; the
//      re-tile is unreachable at source level.
// R17: REVERT to R14 exactly (best verified). k1's residual ~41us is the
//      dependency-serialized per-wave chain; 8 variants failed to compress it.

constexpr int B_   = 32;
constexpr int C_   = 128;
constexpr int N_   = 4096;
constexpr int NSUB = 8;     // 64-wide n-subtiles per k1 block
constexpr int TPB_ = 8;     // k1 blocks per batch (4096 / 512)

using short8  = __attribute__((ext_vector_type(8))) short;
using short4v = __attribute__((ext_vector_type(4))) short;
using float4v = __attribute__((ext_vector_type(4))) float;

__device__ __forceinline__ unsigned short bf16_rne(float f) {
    union { float f; uint32_t u; } v; v.f = f;
    uint32_t u = v.u;
    u += 0x7FFFu + ((u >> 16) & 1u);   // round-to-nearest-even
    return (unsigned short)(u >> 16);
}
__device__ __forceinline__ float bf2f(unsigned short h) {
    union { uint32_t u; float f; } v; v.u = ((uint32_t)h) << 16; return v.f;
}

// workspace layout (bytes)
constexpr size_t OFF_SP   = 0;          // S partials [b][8][128] f32: 131072
constexpr size_t OFF_CTXP = 131072;     // ctx partials [b][8][4096] f32: 4194304 -> 4325376
constexpr size_t OFF_WBIG = 4325376;    // Wbig bf16 TILED: 1048576 -> 5373952
constexpr size_t OFF_QSM  = 5373952;    // q-softmax bf16 [b][n][h*32+d]: 33554432 -> 38928384
// total 38,928,384 bytes

// K1: per (b, 512-wide n-tile): 16 waves. Waves 0-11: gemm wave w owns qkv row-pair w
// (rows w*32..w*32+31); wq fragments converted from f32 Wqkv ONCE per block into
// persistent registers. Waves 12-15: stage x subtiles (T14 issue-early/write-late,
// double-buffered xs). S accumulated in k-wave registers.
__global__ __launch_bounds__(1024) void k1_qkv(const float* __restrict__ x,
                                               const float* __restrict__ Wqkv,
                                               unsigned short* __restrict__ qsm,
                                               float* __restrict__ ctx_part,
                                               float* __restrict__ S_part) {
    __shared__ __align__(16) unsigned short xs0[64 * 136];   // [n][c], stride 136 (dbuf A)
    __shared__ __align__(16) unsigned short xs1[64 * 136];   // dbuf B
    __shared__ __align__(16) unsigned short ek[128 * 72];    // [h*32+d][n], stride 72
    __shared__ __align__(16) unsigned short vsh[128 * 72];   // [h*32+e][n]

    const int b    = blockIdx.y;
    const int tblk = blockIdx.x;                 // 0..7
    const int tid  = threadIdx.x;

    const int lane = tid & 63;
    const int wv   = tid >> 6;                   // 0..15
    const int l15  = lane & 15;
    const int quad = lane >> 4;

    const float4v zero = {0.f, 0.f, 0.f, 0.f};

    // --- persistent wq fragments: f32 load + RNE convert, once per block ---
    short8 wfa[8];                               // [half(0: rows +0..15, 1: +16..31)*4 + kk]
    if (wv < 12) {
        const float* wqp = Wqkv + (wv * 32 + l15) * C_ + quad * 8;
        #pragma unroll
        for (int kk = 0; kk < 4; kk++) {
            float4v a0 = *(const float4v*)(wqp + kk * 32);
            float4v a1 = *(const float4v*)(wqp + kk * 32 + 4);
            float4v b0 = *(const float4v*)(wqp + 16 * C_ + kk * 32);
            float4v b1 = *(const float4v*)(wqp + 16 * C_ + kk * 32 + 4);
            short8 lo, hi;
            #pragma unroll
            for (int j = 0; j < 4; j++) {
                lo[j]     = (short)bf16_rne(a0[j]);
                lo[4 + j] = (short)bf16_rne(a1[j]);
                hi[j]     = (short)bf16_rne(b0[j]);
                hi[4 + j] = (short)bf16_rne(b1[j]);
            }
            wfa[kk]     = lo;
            wfa[4 + kk] = hi;
        }
    }

    // --- staging lanes (waves 12-15): 256 threads, each 32 c-rows of one n ---
    const int sid = tid & 255;                   // for wv>=12: 0..255
    const int snl = sid & 63;                    // n within subtile
    const int scg = sid >> 6;                    // c group of 32
    const float* xbase = x + ((size_t)b * C_ + (size_t)scg * 32) * N_ + snl;
    float xv[32];                                // raw loads (issued one phase early)
    short8 c16[4];                               // converted subtile, write-late
    auto load_x = [&](int s) {
        const float* xp = xbase + (tblk * NSUB + s) * 64;
        #pragma unroll
        for (int i = 0; i < 32; i++) xv[i] = xp[(size_t)i * N_];
    };
    auto conv_x = [&]() {
        #pragma unroll
        for (int ii = 0; ii < 4; ii++) {
            short8 v8;
            #pragma unroll
            for (int j = 0; j < 8; j++) v8[j] = (short)bf16_rne(xv[ii * 8 + j]);
            c16[ii] = v8;
        }
    };
    auto store_c = [&](unsigned short* xs) {
        unsigned short* dst = &xs[snl * 136 + scg * 32];
        #pragma unroll
        for (int ii = 0; ii < 4; ii++) *(short8*)(dst + ii * 8) = c16[ii];
    };

    if (wv >= 12) {
        load_x(0); conv_x(); store_c(xs0);       // subtile 0 staged
        load_x(1);                               // subtile 1 loads in flight into phase 0
    }
    unsigned short* xs_cur = xs0;
    unsigned short* xs_nxt = xs1;

    float4v cacc = zero;                         // this wave's single ctx tile
    float sk0[4] = {0.f, 0.f, 0.f, 0.f};         // S partial accum (k waves only)
    float sk1[4] = {0.f, 0.f, 0.f, 0.f};
    const int ch  = wv >> 2;                     // ctx tile coords (valid for all 16 wv)
    const int cdt = (wv >> 1) & 1;
    const int cet = wv & 1;

    for (int s = 0; s < NSUB; s++) {
        const int ns = (tblk * NSUB + s) * 64;
        __syncthreads();                         // A: xs_cur staged; ek/vsh free

        if (wv < 12) {
            #pragma unroll
            for (int ct = 0; ct < 4; ct++) {
                short8 bfx[4];
                #pragma unroll
                for (int kk = 0; kk < 4; kk++)
                    bfx[kk] = *(const short8*)&xs_cur[(ct * 16 + l15) * 136 + kk * 32 + quad * 8];
                float4v acc0 = zero, acc1 = zero;
                #pragma unroll
                for (int kk = 0; kk < 4; kk++) {
                    acc0 = __builtin_amdgcn_mfma_f32_16x16x32_bf16(wfa[kk],     bfx[kk], acc0, 0, 0, 0);
                    acc1 = __builtin_amdgcn_mfma_f32_16x16x32_bf16(wfa[4 + kk], bfx[kk], acc1, 0, 0, 0);
                }
                const int ncol = ct * 16 + l15;
                // C/D layout: col = l15, row = quad*4 + r (acc0: rows 0-15, acc1: 16-31)
                if (wv < 4) {                    // q, head h = wv: softmax over d per column
                    float e0[4], e1[4], z = 0.f;
                    #pragma unroll
                    for (int r = 0; r < 4; r++) {
                        e0[r] = __expf(acc0[r]); e1[r] = __expf(acc1[r]);
                        z += e0[r] + e1[r];
                    }
                    z += __shfl_xor(z, 16, 64);
                    z += __shfl_xor(z, 32, 64);
                    const float iz = 1.0f / z;
                    unsigned short* qp = qsm + ((size_t)b * N_ + ns + ncol) * C_ + wv * 32 + quad * 4;
                    short4v s0, s1;
                    #pragma unroll
                    for (int r = 0; r < 4; r++) {
                        s0[r] = (short)bf16_rne(e0[r] * iz);
                        s1[r] = (short)bf16_rne(e1[r] * iz);
                    }
                    *(short4v*)qp = s0;          // d = quad*4..+3
                    *(short4v*)(qp + 16) = s1;   // d = 16+quad*4..+3
                } else if (wv < 8) {             // k, head h = wv-4: exp -> LDS + S accum
                    const int row0 = (wv - 4) * 32 + quad * 4;
                    #pragma unroll
                    for (int r = 0; r < 4; r++) {
                        const float e0v = __expf(acc0[r]);
                        const float e1v = __expf(acc1[r]);
                        sk0[r] += e0v;
                        sk1[r] += e1v;
                        ek[(row0 + r) * 72 + ncol]      = bf16_rne(e0v);
                        ek[(row0 + 16 + r) * 72 + ncol] = bf16_rne(e1v);
                    }
                } else {                         // v, head h = wv-8 -> LDS
                    const int row0 = (wv - 8) * 32 + quad * 4;
                    #pragma unroll
                    for (int r = 0; r < 4; r++) {
                        vsh[(row0 + r) * 72 + ncol]      = bf16_rne(acc0[r]);
                        vsh[(row0 + 16 + r) * 72 + ncol] = bf16_rne(acc1[r]);
                    }
                }
            }
        } else {
            if (s + 1 < NSUB) { conv_x(); store_c(xs_nxt); }  // loads from phase s-1
            if (s + 2 < NSUB) load_x(s + 2);                  // issue only; consumed next phase
        }
        __syncthreads();                         // B: ek/vsh ready; xs_nxt staged

        // context: cacc[d][e] += sum_n expk[d][n] * v[e][n]  (one 16x16 tile per wave)
        {
            const unsigned short* ap = &ek[(ch * 32 + cdt * 16 + l15) * 72 + quad * 8];
            const unsigned short* bp = &vsh[(ch * 32 + cet * 16 + l15) * 72 + quad * 8];
            #pragma unroll
            for (int kk = 0; kk < 2; kk++) {
                short8 a  = *(const short8*)(ap + kk * 32);
                short8 bb = *(const short8*)(bp + kk * 32);
                cacc = __builtin_amdgcn_mfma_f32_16x16x32_bf16(a, bb, cacc, 0, 0, 0);
            }
        }
        { unsigned short* t = xs_cur; xs_cur = xs_nxt; xs_nxt = t; }
    }

    // write-out: plain stores, no atomics
    {
        float* cp = ctx_part + ((size_t)(b * TPB_ + tblk) << 12)
                  + ((ch * 32 + cdt * 16 + quad * 4) * 32 + cet * 16 + l15);
        #pragma unroll
        for (int r = 0; r < 4; r++) cp[r * 32] = cacc[r];
    }
    // S: k-waves reduce their register partials over the 16-lane column group
    if (wv >= 4 && wv < 8) {
        const int srow = (wv - 4) * 32 + quad * 4;
        float* sp = S_part + (size_t)(b * TPB_ + tblk) * 128;
        #pragma unroll
        for (int r = 0; r < 4; r++) {
            float a0 = sk0[r], a1 = sk1[r];
            a0 += __shfl_xor(a0, 1, 64); a0 += __shfl_xor(a0, 2, 64);
            a0 += __shfl_xor(a0, 4, 64); a0 += __shfl_xor(a0, 8, 64);
            a1 += __shfl_xor(a1, 1, 64); a1 += __shfl_xor(a1, 2, 64);
            a1 += __shfl_xor(a1, 4, 64); a1 += __shfl_xor(a1, 8, 64);
            if (l15 == 0) { sp[srow + r] = a0; sp[srow + 16 + r] = a1; }
        }
    }
}

// K2 (fused): one block per batch, 512 thr.
// Phase 1: Sinv[128]. Phase 2: reduce 8 ctx partials, *Sinv, bf16 -> LDS ctxb
// [128][40] (stride-40 shorts: 16B-aligned b128 reads — R6-proven). Phase 3:
// Wbig[o][hd] = sum_e Wout[o][h*32+e] * ctxN[hd][e] via 8 MFMAs/wave, Wout frags
// converted f32->bf16 in registers; written FRAG-MAJOR (chunk c = (o>>4)*4+(hd>>5))
// so k3 stages linearly and reads lane-contiguous ds_read_b128.
__global__ __launch_bounds__(512) void k2_fused(const float* __restrict__ ctx_part,
                                                const float* __restrict__ S_part,
                                                const float* __restrict__ Wout,
                                                unsigned short* __restrict__ wbig) {
    __shared__ float Sinv[128];
    __shared__ __align__(16) unsigned short ctxb[128 * 40];  // [h*32+d][e]
    const int b   = blockIdx.x;
    const int tid = threadIdx.x;

    if (tid < 128) {
        float s = 0.f;
        #pragma unroll
        for (int t = 0; t < TPB_; t++)
            s += S_part[(size_t)(b * TPB_ + t) * 128 + tid];
        Sinv[tid] = 1.0f / s;
    }
    __syncthreads();

    #pragma unroll
    for (int i = 0; i < 8; i++) {
        const int ei = i * 512 + tid;            // flat [hd][e]
        float v = 0.f;
        #pragma unroll
        for (int t = 0; t < TPB_; t++)
            v += ctx_part[((size_t)(b * TPB_ + t) << 12) + ei];
        ctxb[(ei >> 5) * 40 + (ei & 31)] = bf16_rne(v * Sinv[ei >> 5]);
    }
    __syncthreads();

    const int lane = tid & 63, wv = tid >> 6, l15 = lane & 15, quad = lane >> 4;
    const float4v zero = {0.f, 0.f, 0.f, 0.f};

    short8 a4[4];                                // Wout frags, f32 load + RNE convert
    {
        const float* wop = Wout + (wv * 16 + l15) * C_ + quad * 8;
        #pragma unroll
        for (int h = 0; h < 4; h++) {
            float4v f0 = *(const float4v*)(wop + h * 32);
            float4v f1 = *(const float4v*)(wop + h * 32 + 4);
            short8 w;
            #pragma unroll
            for (int j = 0; j < 4; j++) {
                w[j]     = (short)bf16_rne(f0[j]);
                w[4 + j] = (short)bf16_rne(f1[j]);
            }
            a4[h] = w;
        }
    }

    unsigned short* wb = wbig + (size_t)b * (C_ * C_);
    #pragma unroll
    for (int ht = 0; ht < 8; ht++) {             // hd-tile: head ht>>1, d-half ht&1
        const int h_ = ht >> 1;
        short8 bb = *(const short8*)&ctxb[(h_ * 32 + (ht & 1) * 16 + l15) * 40 + quad * 8];
        float4v c4 = __builtin_amdgcn_mfma_f32_16x16x32_bf16(a4[h_], bb, zero, 0, 0, 0);
        // value (r): o = wv*16+quad*4+r, hd = ht*16+l15
        const int c     = wv * 4 + (ht >> 1);
        const int quadp = (ht & 1) * 2 + (l15 >> 3);
        #pragma unroll
        for (int r = 0; r < 4; r++)
            wb[((c * 64 + quadp * 16 + quad * 4 + r) << 3) + (l15 & 7)] = bf16_rne(c4[r]);
    }
}

// K3: grid-stride persistent y = Wbig[b] @ qsm + bout, LayerNorm over c.
// 512 blocks (2/CU) x 512 thr; each block owns 256 n-cols = 2 tiles of 128.
// wbig (32KB frag-major) + bout/lnw/lnb staged into LDS ONCE per block; per tile the
// next tile's qsm frags are prefetched before the MFMA+store phase. One barrier total.
__global__ __launch_bounds__(512) void k3_out(const unsigned short* __restrict__ qsm,
                                              const unsigned short* __restrict__ wbig,
                                              const float* __restrict__ bout,
                                              const float* __restrict__ lnw,
                                              const float* __restrict__ lnb,
                                              float* __restrict__ out) {
    __shared__ __align__(16) unsigned short wls[16384];      // 32KB
    __shared__ float lnp[384];                               // bout | lnw | lnb

    const int b    = blockIdx.y;
    const int tseg = blockIdx.x;                 // 0..15: n-cols tseg*256 .. +255
    const int tid  = threadIdx.x;

    const int lane = tid & 63, wv = tid >> 6, l15 = lane & 15, quad = lane >> 4;
    const int nl = wv * 16 + l15;                // 0..127 within tile

    const float4v zero = {0.f, 0.f, 0.f, 0.f};
    const size_t n0base = (size_t)tseg * 256;

    // stage Wbig[b] 32KB -> LDS (linear: thread t copies 16B chunks t, t+512, ...)
    short8 st[4];
    {
        const short8* src = (const short8*)(wbig + (size_t)b * (C_ * C_));
        #pragma unroll
        for (int i = 0; i < 4; i++) st[i] = src[i * 512 + tid];
    }
    if (tid < 128) {
        lnp[tid]       = bout[tid];
        lnp[128 + tid] = lnw[tid];
        lnp[256 + tid] = lnb[tid];
    }
    // first tile's qsm B-frags (independent; overlap the stage)
    short8 bq[4], bqn[4];
    {
        const unsigned short* qp = qsm + ((size_t)b * N_ + n0base + nl) * C_ + quad * 8;
        #pragma unroll
        for (int kk = 0; kk < 4; kk++) bq[kk] = *(const short8*)(qp + kk * 32);
    }
    #pragma unroll
    for (int i = 0; i < 4; i++)
        *(short8*)&wls[(i * 512 + tid) * 8] = st[i];
    __syncthreads();

    #pragma unroll
    for (int t = 0; t < 2; t++) {
        const size_t n = n0base + t * 128 + nl;
        if (t == 0) {                            // prefetch next tile's frags
            const unsigned short* qp = qsm + ((size_t)b * N_ + n0base + 128 + nl) * C_ + quad * 8;
            #pragma unroll
            for (int kk = 0; kk < 4; kk++) bqn[kk] = *(const short8*)(qp + kk * 32);
        }

        float4v acc[8];
        #pragma unroll
        for (int ot = 0; ot < 8; ot++) {
            float4v a = zero;
            #pragma unroll
            for (int kk = 0; kk < 4; kk++) {
                short8 w = *(const short8*)&wls[((ot * 4 + kk) * 64 + lane) * 8];
                a = __builtin_amdgcn_mfma_f32_16x16x32_bf16(w, bq[kk], a, 0, 0, 0);
            }
            acc[ot] = a;
        }

        // bias + LayerNorm over the 128 channels of this column
        float sum = 0.f, sq = 0.f;
        #pragma unroll
        for (int ot = 0; ot < 8; ot++) {
            #pragma unroll
            for (int r = 0; r < 4; r++) {
                const int o = ot * 16 + quad * 4 + r;
                const float y = acc[ot][r] + lnp[o];
                acc[ot][r] = y;
                sum += y; sq += y * y;
            }
        }
        sum += __shfl_xor(sum, 16, 64);
        sum += __shfl_xor(sum, 32, 64);
        sq  += __shfl_xor(sq, 16, 64);
        sq  += __shfl_xor(sq, 32, 64);
        const float mean = sum * (1.0f / 128.0f);
        const float var  = sq * (1.0f / 128.0f) - mean * mean;   // biased, matches jnp.var
        const float rstd = rsqrtf(var + 1e-5f);

        #pragma unroll
        for (int ot = 0; ot < 8; ot++) {
            #pragma unroll
            for (int r = 0; r < 4; r++) {
                const int o = ot * 16 + quad * 4 + r;
                out[((size_t)b * C_ + o) * N_ + n] = (acc[ot][r] - mean) * rstd * lnp[128 + o] + lnp[256 + o];
            }
        }

        #pragma unroll
        for (int kk = 0; kk < 4; kk++) bq[kk] = bqn[kk];
    }
}

extern "C" void kernel_launch(void* const* d_in, const int* in_sizes, int n_in,
                              void* d_out, int out_size, void* d_ws, size_t ws_size,
                              hipStream_t stream) {
    const float* x    = (const float*)d_in[0];
    const float* Wqkv = (const float*)d_in[1];
    const float* Wout = (const float*)d_in[2];
    const float* bout = (const float*)d_in[3];
    const float* lnw  = (const float*)d_in[4];
    const float* lnb  = (const float*)d_in[5];
    float* out = (float*)d_out;

    char* ws = (char*)d_ws;
    float* S_part        = (float*)(ws + OFF_SP);
    float* ctx_part      = (float*)(ws + OFF_CTXP);
    unsigned short* wbig = (unsigned short*)(ws + OFF_WBIG);
    unsigned short* qsm  = (unsigned short*)(ws + OFF_QSM);

    k1_qkv<<<dim3(TPB_, B_), 1024, 0, stream>>>(x, Wqkv, qsm, ctx_part, S_part);
    k2_fused<<<B_, 512, 0, stream>>>(ctx_part, S_part, Wout, wbig);
    k3_out<<<dim3(16, B_), 512, 0, stream>>>(qsm, wbig, bout, lnw, lnb, out);
}